// Round 1
// baseline (2080.602 us; speedup 1.0000x reference)
//
#include <hip/hip_runtime.h>
#include <hip/hip_bf16.h>
#include <cstdint>
#include <cstddef>

#define N_NODES 10000
#define N_EDGES 320000
#define N_GRAPHS 64
#define KCHEB 10
#define C_IN 128
#define C_HID 256
#define C_OUTC 128

static inline size_t align_up(size_t v, size_t a){ return (v + a - 1) / a * a; }

// ---------------- graph setup kernels ----------------

__global__ void k_deg(const int* __restrict__ src, const int* __restrict__ dst,
                      int* __restrict__ deg, int* __restrict__ indeg){
  int e = blockIdx.x*blockDim.x + threadIdx.x;
  if(e < N_EDGES){
    atomicAdd(&deg[src[e]], 1);
    atomicAdd(&indeg[dst[e]], 1);
  }
}

__global__ void k_dis(const int* __restrict__ deg, float* __restrict__ dis){
  int i = blockIdx.x*blockDim.x + threadIdx.x;
  if(i < N_NODES){
    int d = deg[i];
    dis[i] = d > 0 ? rsqrtf((float)d) : 0.f;
  }
}

__global__ void k_edgew(const int* __restrict__ src, const int* __restrict__ dst,
                        const float* __restrict__ dis, float* __restrict__ w){
  int e = blockIdx.x*blockDim.x + threadIdx.x;
  if(e < N_EDGES){
    w[e] = -dis[src[e]] * dis[dst[e]];
  }
}

// exclusive scan over indeg -> offs (and cursor copy). single block, 1024 threads.
__global__ __launch_bounds__(1024) void k_scan(const int* __restrict__ cnt,
                                               int* __restrict__ offs,
                                               int* __restrict__ cursor){
  __shared__ int part[1024];
  const int n = N_NODES;
  const int CH = (n + 1023) / 1024;  // 10
  int tid = threadIdx.x;
  int base = tid * CH;
  int s = 0;
  for(int i = 0; i < CH; i++){
    int idx = base + i;
    if(idx < n) s += cnt[idx];
  }
  part[tid] = s;
  __syncthreads();
  // Hillis-Steele inclusive scan
  for(int off = 1; off < 1024; off <<= 1){
    int v = (tid >= off) ? part[tid - off] : 0;
    __syncthreads();
    part[tid] += v;
    __syncthreads();
  }
  int run = (tid == 0) ? 0 : part[tid - 1];
  for(int i = 0; i < CH; i++){
    int idx = base + i;
    if(idx < n){
      offs[idx] = run;
      cursor[idx] = run;
      run += cnt[idx];
    }
  }
  if(tid == 1023) offs[n] = part[1023];
}

__global__ void k_scatter(const int* __restrict__ src, const int* __restrict__ dst,
                          const float* __restrict__ w, int* __restrict__ cursor,
                          int* __restrict__ csr_s, float* __restrict__ csr_w){
  int e = blockIdx.x*blockDim.x + threadIdx.x;
  if(e < N_EDGES){
    int d = dst[e];
    int p = atomicAdd(&cursor[d], 1);
    csr_s[p] = src[e];
    csr_w[p] = w[e];
  }
}

// ---------------- propagation: out[i,:] = alpha * sum_j w_j * X[src_j,:] - prev[i,:] ----------------

template<int C>
__global__ __launch_bounds__(C) void k_prop(float* __restrict__ out,
                                            const float* __restrict__ X,
                                            const float* __restrict__ prev,
                                            const int* __restrict__ csr_s,
                                            const float* __restrict__ csr_w,
                                            const int* __restrict__ offs,
                                            float alpha){
  int i = blockIdx.x;
  int c = threadIdx.x;
  int j0 = offs[i], j1 = offs[i + 1];
  float acc = 0.f;
  int j = j0;
  for(; j + 1 < j1; j += 2){
    int   s0 = csr_s[j],   s1 = csr_s[j + 1];
    float w0 = csr_w[j],   w1 = csr_w[j + 1];
    acc += w0 * X[(size_t)s0 * C + c];
    acc += w1 * X[(size_t)s1 * C + c];
  }
  if(j < j1){
    acc += csr_w[j] * X[(size_t)csr_s[j] * C + c];
  }
  float r = alpha * acc;
  if(prev) r -= prev[(size_t)i * C + c];
  out[(size_t)i * C + c] = r;
}

// ---------------- GEMM: C(MxN) += A(MxK) @ B(KxN), row-major, fp32 ----------------

#define BM 64
#define BN 64
#define BK 16

__global__ __launch_bounds__(256) void k_gemm_acc(const float* __restrict__ A,
                                                  const float* __restrict__ B,
                                                  float* __restrict__ Cm,
                                                  int M, int Ncols, int Kdim){
  __shared__ float As[BK][BM + 1];
  __shared__ float Bs[BK][BN];
  int tid = threadIdx.x;
  int tx = tid & 15, ty = tid >> 4;
  int row0 = blockIdx.x * BM, col0 = blockIdx.y * BN;
  float acc[4][4] = {};
  int arow = tid >> 2, acol = (tid & 3) * 4;  // A tile: 64 rows x 16 cols
  int brow = ty,       bcol = tx * 4;          // B tile: 16 rows x 64 cols

  for(int k0 = 0; k0 < Kdim; k0 += BK){
    float4 av = make_float4(0.f, 0.f, 0.f, 0.f);
    int ar = row0 + arow;
    if(ar < M){
      av = *(const float4*)(A + (size_t)ar * Kdim + k0 + acol);
    }
    As[acol + 0][arow] = av.x;
    As[acol + 1][arow] = av.y;
    As[acol + 2][arow] = av.z;
    As[acol + 3][arow] = av.w;
    float4 bv = *(const float4*)(B + (size_t)(k0 + brow) * Ncols + col0 + bcol);
    *(float4*)&Bs[brow][bcol] = bv;
    __syncthreads();
#pragma unroll
    for(int kk = 0; kk < BK; kk++){
      float a[4], b[4];
#pragma unroll
      for(int i = 0; i < 4; i++) a[i] = As[kk][ty * 4 + i];
#pragma unroll
      for(int jj = 0; jj < 4; jj++) b[jj] = Bs[kk][tx * 4 + jj];
#pragma unroll
      for(int i = 0; i < 4; i++)
#pragma unroll
        for(int jj = 0; jj < 4; jj++)
          acc[i][jj] += a[i] * b[jj];
    }
    __syncthreads();
  }
#pragma unroll
  for(int i = 0; i < 4; i++){
    int r = row0 + ty * 4 + i;
    if(r < M){
      float4* cp = (float4*)(Cm + (size_t)r * Ncols + col0 + tx * 4);
      float4 cv = *cp;
      cv.x += acc[i][0]; cv.y += acc[i][1]; cv.z += acc[i][2]; cv.w += acc[i][3];
      *cp = cv;
    }
  }
}

// ---------------- misc elementwise ----------------

__global__ void k_bias_init(float* __restrict__ out, const float* __restrict__ b, int n, int Cmask){
  int idx = blockIdx.x*blockDim.x + threadIdx.x;
  if(idx < n) out[idx] = b[idx & Cmask];
}

__global__ void k_relu(float* __restrict__ x, int n){
  int idx = blockIdx.x*blockDim.x + threadIdx.x;
  if(idx < n) x[idx] = fmaxf(x[idx], 0.f);
}

// ---------------- pooling + head ----------------

__global__ void k_ghist(const int* __restrict__ batch, int* __restrict__ gcnt){
  int i = blockIdx.x*blockDim.x + threadIdx.x;
  if(i < N_NODES) atomicAdd(&gcnt[batch[i]], 1);
}

__global__ void k_gscan(const int* __restrict__ gcnt, int* __restrict__ gstart){
  if(threadIdx.x == 0){
    int r = 0;
    for(int g = 0; g < N_GRAPHS; g++){ gstart[g] = r; r += gcnt[g]; }
    gstart[N_GRAPHS] = r;
  }
}

// batch is sorted, so each graph's nodes are a contiguous range
__global__ __launch_bounds__(128) void k_pool(const float* __restrict__ h,
                                              const int* __restrict__ gstart,
                                              const int* __restrict__ gcnt,
                                              float* __restrict__ pooled){
  int g = blockIdx.x;
  int c = blockIdx.y * 128 + threadIdx.x;
  int s = gstart[g], cnt = gcnt[g];
  float acc = 0.f;
  for(int i = 0; i < cnt; i++) acc += h[(size_t)(s + i) * C_HID + c];
  pooled[g * C_HID + c] = acc / fmaxf((float)cnt, 1.f);
}

__global__ __launch_bounds__(128) void k_final(const float* __restrict__ pooled,
                                               const float* __restrict__ Wout,
                                               const float* __restrict__ bout,
                                               float* __restrict__ out){
  int g = blockIdx.x;
  int o = threadIdx.x;
  float acc = bout[o];
  for(int c = 0; c < C_HID; c++) acc += pooled[g * C_HID + c] * Wout[c * C_OUTC + o];
  out[g * C_OUTC + o] = acc;
}

// ---------------- host ----------------

extern "C" void kernel_launch(void* const* d_in, const int* in_sizes, int n_in,
                              void* d_out, int out_size, void* d_ws, size_t ws_size,
                              hipStream_t stream){
  const float* x    = (const float*)d_in[0];
  const float* W0   = (const float*)d_in[1];
  const float* b0   = (const float*)d_in[2];
  const float* W1   = (const float*)d_in[3];
  const float* b1   = (const float*)d_in[4];
  const float* W2   = (const float*)d_in[5];
  const float* b2   = (const float*)d_in[6];
  const float* Wout = (const float*)d_in[7];
  const float* bout = (const float*)d_in[8];
  const int*   ei   = (const int*)d_in[9];
  const int*   batch= (const int*)d_in[10];
  const int* src = ei;
  const int* dst = ei + N_EDGES;
  float* out = (float*)d_out;

  char* p = (char*)d_ws;
  auto alloc = [&](size_t bytes)->char*{ char* r = p; p += align_up(bytes, 256); return r; };

  int*   deg    = (int*)  alloc(N_NODES * 4);
  int*   indeg  = (int*)  alloc(N_NODES * 4);
  int*   offs   = (int*)  alloc((N_NODES + 1) * 4);
  int*   cursor = (int*)  alloc(N_NODES * 4);
  float* dis    = (float*)alloc(N_NODES * 4);
  float* w_e    = (float*)alloc(N_EDGES * 4);
  int*   csr_s  = (int*)  alloc(N_EDGES * 4);
  float* csr_w  = (float*)alloc(N_EDGES * 4);
  int*   gcnt   = (int*)  alloc(N_GRAPHS * 4);
  int*   gstart = (int*)  alloc((N_GRAPHS + 1) * 4);
  float* pooled = (float*)alloc(N_GRAPHS * C_HID * 4);
  float* P0 = (float*)alloc((size_t)N_NODES * C_HID * 4);
  float* P1 = (float*)alloc((size_t)N_NODES * C_HID * 4);
  float* P2 = (float*)alloc((size_t)N_NODES * C_HID * 4);
  float* P3 = (float*)alloc((size_t)N_NODES * C_HID * 4);
  float* P4 = (float*)alloc((size_t)N_NODES * C_HID * 4);

  hipMemsetAsync(deg,   0, N_NODES * 4, stream);
  hipMemsetAsync(indeg, 0, N_NODES * 4, stream);
  hipMemsetAsync(gcnt,  0, N_GRAPHS * 4, stream);

  const int TB = 256;
  int egrid = (N_EDGES + TB - 1) / TB;
  int ngrid = (N_NODES + TB - 1) / TB;

  k_deg<<<egrid, TB, 0, stream>>>(src, dst, deg, indeg);
  k_dis<<<ngrid, TB, 0, stream>>>(deg, dis);
  k_edgew<<<egrid, TB, 0, stream>>>(src, dst, dis, w_e);
  k_scan<<<1, 1024, 0, stream>>>(indeg, offs, cursor);
  k_scatter<<<egrid, TB, 0, stream>>>(src, dst, w_e, cursor, csr_s, csr_w);
  k_ghist<<<ngrid, TB, 0, stream>>>(batch, gcnt);
  k_gscan<<<1, 64, 0, stream>>>(gcnt, gstart);

  auto gemm = [&](const float* A, const float* B, float* Cm, int Kd){
    dim3 grid((N_NODES + BM - 1) / BM, C_HID / BN);
    k_gemm_acc<<<grid, 256, 0, stream>>>(A, B, Cm, N_NODES, C_HID, Kd);
  };

  auto run_layer = [&](const float* X, int Cin, const float* W, const float* b,
                       float* s0, float* s1, float* s2, float* O){
    size_t wstride = (size_t)Cin * C_HID;
    int n_out = N_NODES * C_HID;
    k_bias_init<<<(n_out + TB - 1) / TB, TB, 0, stream>>>(O, b, n_out, C_HID - 1);
    gemm(X, W, O, Cin);                                   // k = 0
    if(Cin == 128)
      k_prop<128><<<N_NODES, 128, 0, stream>>>(s0, X, nullptr, csr_s, csr_w, offs, 1.f);
    else
      k_prop<256><<<N_NODES, 256, 0, stream>>>(s0, X, nullptr, csr_s, csr_w, offs, 1.f);
    gemm(s0, W + wstride, O, Cin);                        // k = 1
    const float* T0 = X;
    float* T1 = s0;
    float* rot[3] = {s0, s1, s2};
    for(int k = 2; k < KCHEB; k++){
      float* T2 = rot[(k - 1) % 3];
      if(Cin == 128)
        k_prop<128><<<N_NODES, 128, 0, stream>>>(T2, T1, T0, csr_s, csr_w, offs, 2.f);
      else
        k_prop<256><<<N_NODES, 256, 0, stream>>>(T2, T1, T0, csr_s, csr_w, offs, 2.f);
      gemm(T2, W + (size_t)k * wstride, O, Cin);
      T0 = T1;
      T1 = T2;
    }
    k_relu<<<(n_out + TB - 1) / TB, TB, 0, stream>>>(O, n_out);
  };

  run_layer(x,  C_IN,  W0, b0, P0, P1, P2, P3);   // h1 in P3 (10000 x 256)
  run_layer(P3, C_HID, W1, b1, P0, P1, P2, P4);   // h2 in P4
  run_layer(P4, C_HID, W2, b2, P0, P1, P2, P3);   // h3 in P3

  dim3 pgrid(N_GRAPHS, C_HID / 128);
  k_pool<<<pgrid, 128, 0, stream>>>(P3, gstart, gcnt, pooled);
  k_final<<<N_GRAPHS, C_OUTC, 0, stream>>>(pooled, Wout, bout, out);
}

// Round 2
// 1456.147 us; speedup vs baseline: 1.4288x; 1.4288x over previous
//
#include <hip/hip_runtime.h>
#include <hip/hip_bf16.h>
#include <cstdint>
#include <cstddef>

#define N_NODES 10000
#define N_EDGES 320000
#define N_GRAPHS 64
#define KCHEB 10
#define C_IN 128
#define C_HID 256
#define C_OUTC 128

static inline size_t align_up(size_t v, size_t a){ return (v + a - 1) / a * a; }

typedef __attribute__((ext_vector_type(8))) short short8;   // 8 bf16 = 4 VGPRs
typedef __attribute__((ext_vector_type(4))) float f32x4;

// ---------------- graph setup kernels ----------------

__global__ void k_deg(const int* __restrict__ src, const int* __restrict__ dst,
                      int* __restrict__ deg, int* __restrict__ indeg){
  int e = blockIdx.x*blockDim.x + threadIdx.x;
  if(e < N_EDGES){
    atomicAdd(&deg[src[e]], 1);
    atomicAdd(&indeg[dst[e]], 1);
  }
}

__global__ void k_dis(const int* __restrict__ deg, float* __restrict__ dis){
  int i = blockIdx.x*blockDim.x + threadIdx.x;
  if(i < N_NODES){
    int d = deg[i];
    dis[i] = d > 0 ? rsqrtf((float)d) : 0.f;
  }
}

__global__ void k_edgew(const int* __restrict__ src, const int* __restrict__ dst,
                        const float* __restrict__ dis, float* __restrict__ w){
  int e = blockIdx.x*blockDim.x + threadIdx.x;
  if(e < N_EDGES){
    w[e] = -dis[src[e]] * dis[dst[e]];
  }
}

// exclusive scan over indeg -> offs (and cursor copy). single block, 1024 threads.
__global__ __launch_bounds__(1024) void k_scan(const int* __restrict__ cnt,
                                               int* __restrict__ offs,
                                               int* __restrict__ cursor){
  __shared__ int part[1024];
  const int n = N_NODES;
  const int CH = (n + 1023) / 1024;  // 10
  int tid = threadIdx.x;
  int base = tid * CH;
  int s = 0;
  for(int i = 0; i < CH; i++){
    int idx = base + i;
    if(idx < n) s += cnt[idx];
  }
  part[tid] = s;
  __syncthreads();
  for(int off = 1; off < 1024; off <<= 1){
    int v = (tid >= off) ? part[tid - off] : 0;
    __syncthreads();
    part[tid] += v;
    __syncthreads();
  }
  int run = (tid == 0) ? 0 : part[tid - 1];
  for(int i = 0; i < CH; i++){
    int idx = base + i;
    if(idx < n){
      offs[idx] = run;
      cursor[idx] = run;
      run += cnt[idx];
    }
  }
  if(tid == 1023) offs[n] = part[1023];
}

__global__ void k_scatter(const int* __restrict__ src, const int* __restrict__ dst,
                          const float* __restrict__ w, int* __restrict__ cursor,
                          int* __restrict__ csr_s, float* __restrict__ csr_w){
  int e = blockIdx.x*blockDim.x + threadIdx.x;
  if(e < N_EDGES){
    int d = dst[e];
    int p = atomicAdd(&cursor[d], 1);
    csr_s[p] = src[e];
    csr_w[p] = w[e];
  }
}

// batch sorted -> graph boundaries by binary search. no atomics.
__global__ __launch_bounds__(128) void k_gbounds(const int* __restrict__ batch,
                                                 int* __restrict__ gstart,
                                                 int* __restrict__ gcnt){
  int g = threadIdx.x;
  if(g <= N_GRAPHS){
    int lo = 0, hi = N_NODES;
    while(lo < hi){
      int mid = (lo + hi) >> 1;
      if(batch[mid] < g) lo = mid + 1; else hi = mid;
    }
    gstart[g] = lo;
  }
  __syncthreads();
  if(g < N_GRAPHS) gcnt[g] = gstart[g + 1] - gstart[g];
}

// ---------------- propagation ----------------
// out[i,:] = alpha * sum_j w_j * X[src_j,:] - (prev ? prev[i,:] : 0)
// also writes bf16 copy of out row into txall (GEMM A-matrix slot)

template<int C>
__global__ __launch_bounds__(C) void k_prop(float* __restrict__ out,
                                            const float* __restrict__ X,
                                            const float* __restrict__ prev,
                                            const int* __restrict__ csr_s,
                                            const float* __restrict__ csr_w,
                                            const int* __restrict__ offs,
                                            float alpha,
                                            __hip_bfloat16* __restrict__ tx,
                                            int tx_stride){
  int i = blockIdx.x;
  int c = threadIdx.x;
  int j0 = offs[i], j1 = offs[i + 1];
  float acc = 0.f;
  int j = j0;
  for(; j + 1 < j1; j += 2){
    int   s0 = csr_s[j],   s1 = csr_s[j + 1];
    float w0 = csr_w[j],   w1 = csr_w[j + 1];
    acc += w0 * X[(size_t)s0 * C + c];
    acc += w1 * X[(size_t)s1 * C + c];
  }
  if(j < j1){
    acc += csr_w[j] * X[(size_t)csr_s[j] * C + c];
  }
  float r = alpha * acc;
  if(prev) r -= prev[(size_t)i * C + c];
  out[(size_t)i * C + c] = r;
  tx[(size_t)i * tx_stride + c] = __float2bfloat16(r);
}

// convert fp32 [rows][C] -> bf16 strided slot
template<int C>
__global__ __launch_bounds__(C) void k_f2bf(const float* __restrict__ X,
                                            __hip_bfloat16* __restrict__ tx,
                                            int tx_stride){
  int i = blockIdx.x;
  int c = threadIdx.x;
  tx[(size_t)i * tx_stride + c] = __float2bfloat16(X[(size_t)i * C + c]);
}

// weight transpose + bf16: WT[o][kc] = W[kc][o], o in [0,256)
__global__ void k_wt(const float* __restrict__ W, __hip_bfloat16* __restrict__ WT, int Ktot){
  int idx = blockIdx.x * blockDim.x + threadIdx.x;
  if(idx < Ktot * 256){
    int o = idx / Ktot;
    int kc = idx - o * Ktot;
    WT[idx] = __float2bfloat16(W[(size_t)kc * 256 + o]);
  }
}

// ---------------- MFMA GEMM ----------------
// O[M][256] = relu( A[M][Ktot](bf16) @ B (given as BT[256][Ktot] bf16) + bias )

#define GBM 64
#define GBN 64
#define GBK 64
#define LDA 72  // padded LDS row (bf16 elems): 144B, 16B-aligned, conflict-free-ish

__global__ __launch_bounds__(256) void k_mfma_gemm(const __hip_bfloat16* __restrict__ A,
                                                   const __hip_bfloat16* __restrict__ BT,
                                                   const float* __restrict__ bias,
                                                   float* __restrict__ O,
                                                   int M, int Ktot, int relu){
  __shared__ short As[GBM * LDA];
  __shared__ short Bs[GBN * LDA];
  int tid = threadIdx.x;
  int lane = tid & 63;
  int wave = tid >> 6;
  int row0 = blockIdx.x * GBM;
  int col0 = blockIdx.y * GBN;
  int wm = (wave & 1) * 32;
  int wn = (wave >> 1) * 32;
  int l15 = lane & 15;
  int quad = lane >> 4;

  f32x4 acc[2][2] = {};

  for(int k0 = 0; k0 < Ktot; k0 += GBK){
#pragma unroll
    for(int i = 0; i < 2; i++){
      int e = tid + i * 256;
      int r = e >> 3;
      int kc = (e & 7) * 8;
      uint4 av = make_uint4(0u, 0u, 0u, 0u);
      int gr = row0 + r;
      if(gr < M) av = *(const uint4*)(A + (size_t)gr * Ktot + k0 + kc);
      *(uint4*)(As + r * LDA + kc) = av;
      uint4 bv = *(const uint4*)(BT + (size_t)(col0 + r) * Ktot + k0 + kc);
      *(uint4*)(Bs + r * LDA + kc) = bv;
    }
    __syncthreads();
#pragma unroll
    for(int kk = 0; kk < GBK; kk += 32){
      short8 a0 = *(const short8*)(As + (wm +      l15) * LDA + kk + quad * 8);
      short8 a1 = *(const short8*)(As + (wm + 16 + l15) * LDA + kk + quad * 8);
      short8 b0 = *(const short8*)(Bs + (wn +      l15) * LDA + kk + quad * 8);
      short8 b1 = *(const short8*)(Bs + (wn + 16 + l15) * LDA + kk + quad * 8);
      acc[0][0] = __builtin_amdgcn_mfma_f32_16x16x32_bf16(a0, b0, acc[0][0], 0, 0, 0);
      acc[0][1] = __builtin_amdgcn_mfma_f32_16x16x32_bf16(a0, b1, acc[0][1], 0, 0, 0);
      acc[1][0] = __builtin_amdgcn_mfma_f32_16x16x32_bf16(a1, b0, acc[1][0], 0, 0, 0);
      acc[1][1] = __builtin_amdgcn_mfma_f32_16x16x32_bf16(a1, b1, acc[1][1], 0, 0, 0);
    }
    __syncthreads();
  }

#pragma unroll
  for(int i = 0; i < 2; i++){
#pragma unroll
    for(int j = 0; j < 2; j++){
#pragma unroll
      for(int r = 0; r < 4; r++){
        int grow = row0 + wm + i * 16 + quad * 4 + r;
        int gcol = col0 + wn + j * 16 + l15;
        if(grow < M){
          float v = acc[i][j][r] + bias[gcol];
          if(relu) v = fmaxf(v, 0.f);
          O[(size_t)grow * C_HID + gcol] = v;
        }
      }
    }
  }
}

// ---------------- pooling + head ----------------

__global__ __launch_bounds__(128) void k_pool(const float* __restrict__ h,
                                              const int* __restrict__ gstart,
                                              const int* __restrict__ gcnt,
                                              float* __restrict__ pooled){
  int g = blockIdx.x;
  int c = blockIdx.y * 128 + threadIdx.x;
  int s = gstart[g], cnt = gcnt[g];
  float acc = 0.f;
  for(int i = 0; i < cnt; i++) acc += h[(size_t)(s + i) * C_HID + c];
  pooled[g * C_HID + c] = acc / fmaxf((float)cnt, 1.f);
}

__global__ __launch_bounds__(128) void k_final(const float* __restrict__ pooled,
                                               const float* __restrict__ Wout,
                                               const float* __restrict__ bout,
                                               float* __restrict__ out){
  int g = blockIdx.x;
  int o = threadIdx.x;
  float acc = bout[o];
  for(int c = 0; c < C_HID; c++) acc += pooled[g * C_HID + c] * Wout[c * C_OUTC + o];
  out[g * C_OUTC + o] = acc;
}

// ---------------- host ----------------

extern "C" void kernel_launch(void* const* d_in, const int* in_sizes, int n_in,
                              void* d_out, int out_size, void* d_ws, size_t ws_size,
                              hipStream_t stream){
  const float* x    = (const float*)d_in[0];
  const float* W0   = (const float*)d_in[1];
  const float* b0   = (const float*)d_in[2];
  const float* W1   = (const float*)d_in[3];
  const float* b1   = (const float*)d_in[4];
  const float* W2   = (const float*)d_in[5];
  const float* b2   = (const float*)d_in[6];
  const float* Wout = (const float*)d_in[7];
  const float* bout = (const float*)d_in[8];
  const int*   ei   = (const int*)d_in[9];
  const int*   batch= (const int*)d_in[10];
  const int* src = ei;
  const int* dst = ei + N_EDGES;
  float* out = (float*)d_out;

  char* p = (char*)d_ws;
  auto alloc = [&](size_t bytes)->char*{ char* r = p; p += align_up(bytes, 256); return r; };

  int*   deg    = (int*)  alloc(N_NODES * 4);
  int*   indeg  = (int*)  alloc(N_NODES * 4);
  int*   offs   = (int*)  alloc((N_NODES + 1) * 4);
  int*   cursor = (int*)  alloc(N_NODES * 4);
  float* dis    = (float*)alloc(N_NODES * 4);
  float* w_e    = (float*)alloc(N_EDGES * 4);
  int*   csr_s  = (int*)  alloc(N_EDGES * 4);
  float* csr_w  = (float*)alloc(N_EDGES * 4);
  int*   gcnt   = (int*)  alloc(N_GRAPHS * 4);
  int*   gstart = (int*)  alloc((N_GRAPHS + 1) * 4);
  float* pooled = (float*)alloc(N_GRAPHS * C_HID * 4);

  __hip_bfloat16* txall = (__hip_bfloat16*)alloc((size_t)N_NODES * (KCHEB * C_HID) * 2); // 51.2 MB
  __hip_bfloat16* WT0   = (__hip_bfloat16*)alloc((size_t)KCHEB * C_IN  * C_HID * 2);
  __hip_bfloat16* WT1   = (__hip_bfloat16*)alloc((size_t)KCHEB * C_HID * C_HID * 2);
  __hip_bfloat16* WT2   = (__hip_bfloat16*)alloc((size_t)KCHEB * C_HID * C_HID * 2);
  float* s0 = (float*)alloc((size_t)N_NODES * C_HID * 4);
  float* s1 = (float*)alloc((size_t)N_NODES * C_HID * 4);
  float* s2 = (float*)alloc((size_t)N_NODES * C_HID * 4);
  float* Hb = (float*)alloc((size_t)N_NODES * C_HID * 4);

  hipMemsetAsync(deg,   0, N_NODES * 4, stream);
  hipMemsetAsync(indeg, 0, N_NODES * 4, stream);

  const int TB = 256;
  int egrid = (N_EDGES + TB - 1) / TB;
  int ngrid = (N_NODES + TB - 1) / TB;

  k_deg<<<egrid, TB, 0, stream>>>(src, dst, deg, indeg);
  k_dis<<<ngrid, TB, 0, stream>>>(deg, dis);
  k_edgew<<<egrid, TB, 0, stream>>>(src, dst, dis, w_e);
  k_scan<<<1, 1024, 0, stream>>>(indeg, offs, cursor);
  k_scatter<<<egrid, TB, 0, stream>>>(src, dst, w_e, cursor, csr_s, csr_w);
  k_gbounds<<<1, 128, 0, stream>>>(batch, gstart, gcnt);

  // weight prep
  {
    int n0 = KCHEB * C_IN  * C_HID;  // 327680
    int n1 = KCHEB * C_HID * C_HID;  // 655360
    k_wt<<<(n0 + TB - 1) / TB, TB, 0, stream>>>(W0, WT0, KCHEB * C_IN);
    k_wt<<<(n1 + TB - 1) / TB, TB, 0, stream>>>(W1, WT1, KCHEB * C_HID);
    k_wt<<<(n1 + TB - 1) / TB, TB, 0, stream>>>(W2, WT2, KCHEB * C_HID);
  }

  auto run_layer = [&](const float* X, int Cin, const __hip_bfloat16* WT, const float* b,
                       float* O, int relu){
    const int Ktot = KCHEB * Cin;
    // Tx0 slot
    if(Cin == C_IN) k_f2bf<C_IN ><<<N_NODES, C_IN,  0, stream>>>(X, txall, Ktot);
    else            k_f2bf<C_HID><<<N_NODES, C_HID, 0, stream>>>(X, txall, Ktot);
    // Tx1
    if(Cin == C_IN)
      k_prop<C_IN ><<<N_NODES, C_IN,  0, stream>>>(s0, X, nullptr, csr_s, csr_w, offs, 1.f,
                                                   txall + 1 * Cin, Ktot);
    else
      k_prop<C_HID><<<N_NODES, C_HID, 0, stream>>>(s0, X, nullptr, csr_s, csr_w, offs, 1.f,
                                                   txall + 1 * Cin, Ktot);
    const float* T0 = X;
    float* T1 = s0;
    float* rot[3] = {s0, s1, s2};
    for(int k = 2; k < KCHEB; k++){
      float* T2 = rot[(k - 1) % 3];
      if(Cin == C_IN)
        k_prop<C_IN ><<<N_NODES, C_IN,  0, stream>>>(T2, T1, T0, csr_s, csr_w, offs, 2.f,
                                                     txall + (size_t)k * Cin, Ktot);
      else
        k_prop<C_HID><<<N_NODES, C_HID, 0, stream>>>(T2, T1, T0, csr_s, csr_w, offs, 2.f,
                                                     txall + (size_t)k * Cin, Ktot);
      T0 = T1;
      T1 = T2;
    }
    dim3 grid((N_NODES + GBM - 1) / GBM, C_HID / GBN);
    k_mfma_gemm<<<grid, 256, 0, stream>>>(txall, WT, b, O, N_NODES, Ktot, relu);
  };

  run_layer(x,  C_IN,  WT0, b0, Hb, 1);
  run_layer(Hb, C_HID, WT1, b1, Hb, 1);  // props consume Hb before GEMM overwrites it
  run_layer(Hb, C_HID, WT2, b2, Hb, 1);

  dim3 pgrid(N_GRAPHS, C_HID / 128);
  k_pool<<<pgrid, 128, 0, stream>>>(Hb, gstart, gcnt, pooled);
  k_final<<<N_GRAPHS, C_OUTC, 0, stream>>>(pooled, Wout, bout, out);
}

// Round 3
// 1137.595 us; speedup vs baseline: 1.8289x; 1.2800x over previous
//
#include <hip/hip_runtime.h>
#include <hip/hip_bf16.h>
#include <cstdint>
#include <cstddef>

#define N_NODES 10000
#define N_EDGES 320000
#define N_GRAPHS 64
#define KCHEB 10
#define C_IN 128
#define C_HID 256
#define C_OUTC 128

static inline size_t align_up(size_t v, size_t a){ return (v + a - 1) / a * a; }

typedef __attribute__((ext_vector_type(8))) short short8;   // 8 bf16 = 4 VGPRs
typedef __attribute__((ext_vector_type(4))) float f32x4;

__device__ inline float bf2f(unsigned int bits16){
  union{ unsigned int i; float f; } v; v.i = bits16 << 16; return v.f;
}
__device__ inline unsigned short f2bf_bits(float f){
  __hip_bfloat16 h = __float2bfloat16(f);
  return *reinterpret_cast<unsigned short*>(&h);
}

// ---------------- graph setup kernels ----------------

__global__ void k_deg(const int* __restrict__ src, const int* __restrict__ dst,
                      int* __restrict__ deg, int* __restrict__ indeg){
  int e = blockIdx.x*blockDim.x + threadIdx.x;
  if(e < N_EDGES){
    atomicAdd(&deg[src[e]], 1);
    atomicAdd(&indeg[dst[e]], 1);
  }
}

__global__ void k_dis(const int* __restrict__ deg, float* __restrict__ dis){
  int i = blockIdx.x*blockDim.x + threadIdx.x;
  if(i < N_NODES){
    int d = deg[i];
    dis[i] = d > 0 ? rsqrtf((float)d) : 0.f;
  }
}

__global__ void k_edgew(const int* __restrict__ src, const int* __restrict__ dst,
                        const float* __restrict__ dis, float* __restrict__ w){
  int e = blockIdx.x*blockDim.x + threadIdx.x;
  if(e < N_EDGES){
    w[e] = -dis[src[e]] * dis[dst[e]];
  }
}

__global__ __launch_bounds__(1024) void k_scan(const int* __restrict__ cnt,
                                               int* __restrict__ offs,
                                               int* __restrict__ cursor){
  __shared__ int part[1024];
  const int n = N_NODES;
  const int CH = (n + 1023) / 1024;
  int tid = threadIdx.x;
  int base = tid * CH;
  int s = 0;
  for(int i = 0; i < CH; i++){
    int idx = base + i;
    if(idx < n) s += cnt[idx];
  }
  part[tid] = s;
  __syncthreads();
  for(int off = 1; off < 1024; off <<= 1){
    int v = (tid >= off) ? part[tid - off] : 0;
    __syncthreads();
    part[tid] += v;
    __syncthreads();
  }
  int run = (tid == 0) ? 0 : part[tid - 1];
  for(int i = 0; i < CH; i++){
    int idx = base + i;
    if(idx < n){
      offs[idx] = run;
      cursor[idx] = run;
      run += cnt[idx];
    }
  }
  if(tid == 1023) offs[n] = part[1023];
}

__global__ void k_scatter(const int* __restrict__ src, const int* __restrict__ dst,
                          const float* __restrict__ w, int* __restrict__ cursor,
                          int* __restrict__ csr_s, float* __restrict__ csr_w){
  int e = blockIdx.x*blockDim.x + threadIdx.x;
  if(e < N_EDGES){
    int d = dst[e];
    int p = atomicAdd(&cursor[d], 1);
    csr_s[p] = src[e];
    csr_w[p] = w[e];
  }
}

__global__ __launch_bounds__(128) void k_gbounds(const int* __restrict__ batch,
                                                 int* __restrict__ gstart,
                                                 int* __restrict__ gcnt){
  int g = threadIdx.x;
  if(g <= N_GRAPHS){
    int lo = 0, hi = N_NODES;
    while(lo < hi){
      int mid = (lo + hi) >> 1;
      if(batch[mid] < g) lo = mid + 1; else hi = mid;
    }
    gstart[g] = lo;
  }
  __syncthreads();
  if(g < N_GRAPHS) gcnt[g] = gstart[g + 1] - gstart[g];
}

// ---------------- propagation ----------------
// out[i,:] = alpha * sum_j w_j * bf16gather(Xb[src_j,:]) - (prev ? prev[i,:] : 0)
// gathers from bf16 slot (half traffic); fp32 recurrence state preserved in out/prev.
// Also writes bf16 copy into tx (next gather source / GEMM A slot).
// One wave per node, 4 nodes per 256-thread block.

__global__ __launch_bounds__(256) void k_prop256(float* __restrict__ out,
                                                 const __hip_bfloat16* __restrict__ Xb,
                                                 const float* __restrict__ prev,
                                                 const int* __restrict__ csr_s,
                                                 const float* __restrict__ csr_w,
                                                 const int* __restrict__ offs,
                                                 float alpha,
                                                 __hip_bfloat16* __restrict__ tx,
                                                 int tx_stride){
  int node = blockIdx.x * 4 + (threadIdx.x >> 6);
  int lane = threadIdx.x & 63;
  int j0 = offs[node], j1 = offs[node + 1];
  float a0 = 0.f, a1 = 0.f, a2 = 0.f, a3 = 0.f;
  const __hip_bfloat16* __restrict__ gbase = Xb + lane * 4;
  int j = j0;
  for(; j + 1 < j1; j += 2){
    int   s0 = csr_s[j],   s1 = csr_s[j + 1];
    float w0 = csr_w[j],   w1 = csr_w[j + 1];
    uint2 v0 = *(const uint2*)(gbase + (size_t)s0 * tx_stride);
    uint2 v1 = *(const uint2*)(gbase + (size_t)s1 * tx_stride);
    a0 += w0 * bf2f(v0.x & 0xffffu); a1 += w0 * bf2f(v0.x >> 16);
    a2 += w0 * bf2f(v0.y & 0xffffu); a3 += w0 * bf2f(v0.y >> 16);
    a0 += w1 * bf2f(v1.x & 0xffffu); a1 += w1 * bf2f(v1.x >> 16);
    a2 += w1 * bf2f(v1.y & 0xffffu); a3 += w1 * bf2f(v1.y >> 16);
  }
  if(j < j1){
    int s0 = csr_s[j]; float w0 = csr_w[j];
    uint2 v0 = *(const uint2*)(gbase + (size_t)s0 * tx_stride);
    a0 += w0 * bf2f(v0.x & 0xffffu); a1 += w0 * bf2f(v0.x >> 16);
    a2 += w0 * bf2f(v0.y & 0xffffu); a3 += w0 * bf2f(v0.y >> 16);
  }
  float r0 = alpha * a0, r1 = alpha * a1, r2 = alpha * a2, r3 = alpha * a3;
  size_t off = (size_t)node * 256 + lane * 4;
  if(prev){
    float4 pv = *(const float4*)(prev + off);
    r0 -= pv.x; r1 -= pv.y; r2 -= pv.z; r3 -= pv.w;
  }
  *(float4*)(out + off) = make_float4(r0, r1, r2, r3);
  uint2 ob;
  ob.x = (unsigned)f2bf_bits(r0) | ((unsigned)f2bf_bits(r1) << 16);
  ob.y = (unsigned)f2bf_bits(r2) | ((unsigned)f2bf_bits(r3) << 16);
  *(uint2*)(tx + (size_t)node * tx_stride + lane * 4) = ob;
}

__global__ __launch_bounds__(256) void k_prop128(float* __restrict__ out,
                                                 const __hip_bfloat16* __restrict__ Xb,
                                                 const float* __restrict__ prev,
                                                 const int* __restrict__ csr_s,
                                                 const float* __restrict__ csr_w,
                                                 const int* __restrict__ offs,
                                                 float alpha,
                                                 __hip_bfloat16* __restrict__ tx,
                                                 int tx_stride){
  int node = blockIdx.x * 4 + (threadIdx.x >> 6);
  int lane = threadIdx.x & 63;
  int j0 = offs[node], j1 = offs[node + 1];
  float a0 = 0.f, a1 = 0.f;
  const __hip_bfloat16* __restrict__ gbase = Xb + lane * 2;
  int j = j0;
  for(; j + 1 < j1; j += 2){
    int   s0 = csr_s[j],   s1 = csr_s[j + 1];
    float w0 = csr_w[j],   w1 = csr_w[j + 1];
    unsigned v0 = *(const unsigned*)(gbase + (size_t)s0 * tx_stride);
    unsigned v1 = *(const unsigned*)(gbase + (size_t)s1 * tx_stride);
    a0 += w0 * bf2f(v0 & 0xffffu); a1 += w0 * bf2f(v0 >> 16);
    a0 += w1 * bf2f(v1 & 0xffffu); a1 += w1 * bf2f(v1 >> 16);
  }
  if(j < j1){
    int s0 = csr_s[j]; float w0 = csr_w[j];
    unsigned v0 = *(const unsigned*)(gbase + (size_t)s0 * tx_stride);
    a0 += w0 * bf2f(v0 & 0xffffu); a1 += w0 * bf2f(v0 >> 16);
  }
  float r0 = alpha * a0, r1 = alpha * a1;
  size_t off = (size_t)node * 128 + lane * 2;
  if(prev){
    float2 pv = *(const float2*)(prev + off);
    r0 -= pv.x; r1 -= pv.y;
  }
  *(float2*)(out + off) = make_float2(r0, r1);
  unsigned ob = (unsigned)f2bf_bits(r0) | ((unsigned)f2bf_bits(r1) << 16);
  *(unsigned*)(tx + (size_t)node * tx_stride + lane * 2) = ob;
}

// fp32 [rows][C] -> bf16 strided slot, vectorized
template<int C>
__global__ void k_f2bf(const float* __restrict__ X, __hip_bfloat16* __restrict__ tx,
                       int tx_stride){
  int idx = blockIdx.x * blockDim.x + threadIdx.x;     // group of 4 elems
  const int GPR = C / 4;
  if(idx < N_NODES * GPR){
    int r = idx / GPR;
    int c = (idx - r * GPR) * 4;
    float4 v = *(const float4*)(X + (size_t)r * C + c);
    uint2 ob;
    ob.x = (unsigned)f2bf_bits(v.x) | ((unsigned)f2bf_bits(v.y) << 16);
    ob.y = (unsigned)f2bf_bits(v.z) | ((unsigned)f2bf_bits(v.w) << 16);
    *(uint2*)(tx + (size_t)r * tx_stride + c) = ob;
  }
}

// weight transpose + bf16: WT[o][kc] = W[kc][o], o in [0,256)
__global__ void k_wt(const float* __restrict__ W, __hip_bfloat16* __restrict__ WT, int Ktot){
  int idx = blockIdx.x * blockDim.x + threadIdx.x;
  if(idx < Ktot * 256){
    int o = idx / Ktot;
    int kc = idx - o * Ktot;
    WT[idx] = __float2bfloat16(W[(size_t)kc * 256 + o]);
  }
}

// ---------------- MFMA GEMM ----------------
// O[M][256] = relu( A[M][Ktot](bf16) @ BT[256][Ktot](bf16)^T + bias )
// Block tile 64(M) x 256(N): A fetched exactly once across the grid.
// XOR-swizzled LDS (stride 64, 8-elem groups g ^= row&7): conflict-minimal.

__global__ __launch_bounds__(256) void k_gemm(const __hip_bfloat16* __restrict__ A,
                                              const __hip_bfloat16* __restrict__ BT,
                                              const float* __restrict__ bias,
                                              float* __restrict__ O,
                                              int M, int Ktot, int relu){
  __shared__ short As[64 * 64];
  __shared__ short Bs[256 * 64];
  int tid = threadIdx.x;
  int lane = tid & 63;
  int wave = tid >> 6;
  int row0 = blockIdx.x * 64;
  int l15 = lane & 15;
  int quad = lane >> 4;
  int wn = wave * 64;

  f32x4 acc[4][4] = {};

  for(int k0 = 0; k0 < Ktot; k0 += 64){
#pragma unroll
    for(int i = 0; i < 2; i++){
      int e = tid + i * 256;
      int r = e >> 3, g = e & 7;
      uint4 v = make_uint4(0u, 0u, 0u, 0u);
      int gr = row0 + r;
      if(gr < M) v = *(const uint4*)(A + (size_t)gr * Ktot + k0 + g * 8);
      *(uint4*)(As + r * 64 + ((g ^ (r & 7)) * 8)) = v;
    }
#pragma unroll
    for(int i = 0; i < 8; i++){
      int e = tid + i * 256;
      int n = e >> 3, g = e & 7;
      uint4 v = *(const uint4*)(BT + (size_t)n * Ktot + k0 + g * 8);
      *(uint4*)(Bs + n * 64 + ((g ^ (n & 7)) * 8)) = v;
    }
    __syncthreads();
#pragma unroll
    for(int kk = 0; kk < 64; kk += 32){
      int g = (kk >> 3) + quad;
      short8 a[4], b[4];
#pragma unroll
      for(int mi = 0; mi < 4; mi++){
        int r = mi * 16 + l15;
        a[mi] = *(const short8*)(As + r * 64 + ((g ^ (r & 7)) * 8));
      }
#pragma unroll
      for(int ni = 0; ni < 4; ni++){
        int n = wn + ni * 16 + l15;
        b[ni] = *(const short8*)(Bs + n * 64 + ((g ^ (n & 7)) * 8));
      }
#pragma unroll
      for(int mi = 0; mi < 4; mi++)
#pragma unroll
        for(int ni = 0; ni < 4; ni++)
          acc[mi][ni] = __builtin_amdgcn_mfma_f32_16x16x32_bf16(a[mi], b[ni], acc[mi][ni], 0, 0, 0);
    }
    __syncthreads();
  }

#pragma unroll
  for(int mi = 0; mi < 4; mi++){
#pragma unroll
    for(int ni = 0; ni < 4; ni++){
      int gcol = wn + ni * 16 + l15;
      float bv = bias[gcol];
#pragma unroll
      for(int r = 0; r < 4; r++){
        int grow = row0 + mi * 16 + quad * 4 + r;
        if(grow < M){
          float v = acc[mi][ni][r] + bv;
          if(relu) v = fmaxf(v, 0.f);
          O[(size_t)grow * C_HID + gcol] = v;
        }
      }
    }
  }
}

// ---------------- pooling + head ----------------

__global__ __launch_bounds__(128) void k_pool(const float* __restrict__ h,
                                              const int* __restrict__ gstart,
                                              const int* __restrict__ gcnt,
                                              float* __restrict__ pooled){
  int g = blockIdx.x;
  int c = blockIdx.y * 128 + threadIdx.x;
  int s = gstart[g], cnt = gcnt[g];
  float acc = 0.f;
  for(int i = 0; i < cnt; i++) acc += h[(size_t)(s + i) * C_HID + c];
  pooled[g * C_HID + c] = acc / fmaxf((float)cnt, 1.f);
}

__global__ __launch_bounds__(128) void k_final(const float* __restrict__ pooled,
                                               const float* __restrict__ Wout,
                                               const float* __restrict__ bout,
                                               float* __restrict__ out){
  int g = blockIdx.x;
  int o = threadIdx.x;
  float acc = bout[o];
  for(int c = 0; c < C_HID; c++) acc += pooled[g * C_HID + c] * Wout[c * C_OUTC + o];
  out[g * C_OUTC + o] = acc;
}

// ---------------- host ----------------

extern "C" void kernel_launch(void* const* d_in, const int* in_sizes, int n_in,
                              void* d_out, int out_size, void* d_ws, size_t ws_size,
                              hipStream_t stream){
  const float* x    = (const float*)d_in[0];
  const float* W0   = (const float*)d_in[1];
  const float* b0   = (const float*)d_in[2];
  const float* W1   = (const float*)d_in[3];
  const float* b1   = (const float*)d_in[4];
  const float* W2   = (const float*)d_in[5];
  const float* b2   = (const float*)d_in[6];
  const float* Wout = (const float*)d_in[7];
  const float* bout = (const float*)d_in[8];
  const int*   ei   = (const int*)d_in[9];
  const int*   batch= (const int*)d_in[10];
  const int* src = ei;
  const int* dst = ei + N_EDGES;
  float* out = (float*)d_out;

  char* p = (char*)d_ws;
  auto alloc = [&](size_t bytes)->char*{ char* r = p; p += align_up(bytes, 256); return r; };

  int*   deg    = (int*)  alloc(N_NODES * 4);
  int*   indeg  = (int*)  alloc(N_NODES * 4);
  int*   offs   = (int*)  alloc((N_NODES + 1) * 4);
  int*   cursor = (int*)  alloc(N_NODES * 4);
  float* dis    = (float*)alloc(N_NODES * 4);
  float* w_e    = (float*)alloc(N_EDGES * 4);
  int*   csr_s  = (int*)  alloc(N_EDGES * 4);
  float* csr_w  = (float*)alloc(N_EDGES * 4);
  int*   gcnt   = (int*)  alloc(N_GRAPHS * 4);
  int*   gstart = (int*)  alloc((N_GRAPHS + 1) * 4);
  float* pooled = (float*)alloc(N_GRAPHS * C_HID * 4);

  __hip_bfloat16* txall = (__hip_bfloat16*)alloc((size_t)N_NODES * (KCHEB * C_HID) * 2);
  __hip_bfloat16* WT0   = (__hip_bfloat16*)alloc((size_t)KCHEB * C_IN  * C_HID * 2);
  __hip_bfloat16* WT1   = (__hip_bfloat16*)alloc((size_t)KCHEB * C_HID * C_HID * 2);
  __hip_bfloat16* WT2   = (__hip_bfloat16*)alloc((size_t)KCHEB * C_HID * C_HID * 2);
  float* s0 = (float*)alloc((size_t)N_NODES * C_HID * 4);
  float* s1 = (float*)alloc((size_t)N_NODES * C_HID * 4);
  float* s2 = (float*)alloc((size_t)N_NODES * C_HID * 4);
  float* Hb = (float*)alloc((size_t)N_NODES * C_HID * 4);

  hipMemsetAsync(deg,   0, N_NODES * 4, stream);
  hipMemsetAsync(indeg, 0, N_NODES * 4, stream);

  const int TB = 256;
  int egrid = (N_EDGES + TB - 1) / TB;
  int ngrid = (N_NODES + TB - 1) / TB;

  k_deg<<<egrid, TB, 0, stream>>>(src, dst, deg, indeg);
  k_dis<<<ngrid, TB, 0, stream>>>(deg, dis);
  k_edgew<<<egrid, TB, 0, stream>>>(src, dst, dis, w_e);
  k_scan<<<1, 1024, 0, stream>>>(indeg, offs, cursor);
  k_scatter<<<egrid, TB, 0, stream>>>(src, dst, w_e, cursor, csr_s, csr_w);
  k_gbounds<<<1, 128, 0, stream>>>(batch, gstart, gcnt);

  {
    int n0 = KCHEB * C_IN  * C_HID;
    int n1 = KCHEB * C_HID * C_HID;
    k_wt<<<(n0 + TB - 1) / TB, TB, 0, stream>>>(W0, WT0, KCHEB * C_IN);
    k_wt<<<(n1 + TB - 1) / TB, TB, 0, stream>>>(W1, WT1, KCHEB * C_HID);
    k_wt<<<(n1 + TB - 1) / TB, TB, 0, stream>>>(W2, WT2, KCHEB * C_HID);
  }

  auto run_layer = [&](const float* X, int Cin, const __hip_bfloat16* WT, const float* b,
                       float* O, int relu){
    const int Ktot = KCHEB * Cin;
    // Tx0 slot (bf16 copy of X)
    if(Cin == C_IN){
      int ng = N_NODES * (C_IN / 4);
      k_f2bf<C_IN><<<(ng + TB - 1) / TB, TB, 0, stream>>>(X, txall, Ktot);
    } else {
      int ng = N_NODES * (C_HID / 4);
      k_f2bf<C_HID><<<(ng + TB - 1) / TB, TB, 0, stream>>>(X, txall, Ktot);
    }
    // Tx1 = L_hat x (gather from bf16 slot 0)
    if(Cin == C_IN)
      k_prop128<<<N_NODES / 4, 256, 0, stream>>>(s0, txall, nullptr, csr_s, csr_w, offs, 1.f,
                                                 txall + 1 * Cin, Ktot);
    else
      k_prop256<<<N_NODES / 4, 256, 0, stream>>>(s0, txall, nullptr, csr_s, csr_w, offs, 1.f,
                                                 txall + 1 * Cin, Ktot);
    const float* T0 = X;
    float* T1 = s0;
    float* rot[3] = {s0, s1, s2};
    for(int k = 2; k < KCHEB; k++){
      float* T2 = rot[(k - 1) % 3];
      const __hip_bfloat16* gsrc = txall + (size_t)(k - 1) * Cin;  // bf16 of T1
      if(Cin == C_IN)
        k_prop128<<<N_NODES / 4, 256, 0, stream>>>(T2, gsrc, T0, csr_s, csr_w, offs, 2.f,
                                                   txall + (size_t)k * Cin, Ktot);
      else
        k_prop256<<<N_NODES / 4, 256, 0, stream>>>(T2, gsrc, T0, csr_s, csr_w, offs, 2.f,
                                                   txall + (size_t)k * Cin, Ktot);
      T0 = T1;
      T1 = T2;
    }
    k_gemm<<<(N_NODES + 63) / 64, 256, 0, stream>>>(txall, WT, b, O, N_NODES, Ktot, relu);
  };

  run_layer(x,  C_IN,  WT0, b0, Hb, 1);
  run_layer(Hb, C_HID, WT1, b1, Hb, 1);
  run_layer(Hb, C_HID, WT2, b2, Hb, 1);

  dim3 pgrid(N_GRAPHS, C_HID / 128);
  k_pool<<<pgrid, 128, 0, stream>>>(Hb, gstart, gcnt, pooled);
  k_final<<<N_GRAPHS, C_OUTC, 0, stream>>>(pooled, Wout, bout, out);
}

// Round 4
// 911.396 us; speedup vs baseline: 2.2829x; 1.2482x over previous
//
#include <hip/hip_runtime.h>
#include <hip/hip_bf16.h>
#include <cstdint>
#include <cstddef>

#define N_NODES 10000
#define N_EDGES 320000
#define N_GRAPHS 64
#define KCHEB 10
#define C_IN 128
#define C_HID 256
#define C_OUTC 128

static inline size_t align_up(size_t v, size_t a){ return (v + a - 1) / a * a; }

typedef __attribute__((ext_vector_type(8))) short short8;   // 8 bf16 = 4 VGPRs
typedef __attribute__((ext_vector_type(4))) float f32x4;

__device__ inline float bf2f(unsigned int bits16){
  union{ unsigned int i; float f; } v; v.i = bits16 << 16; return v.f;
}
__device__ inline unsigned short f2bf_bits(float f){
  __hip_bfloat16 h = __float2bfloat16(f);
  return *reinterpret_cast<unsigned short*>(&h);
}

// ---------------- graph setup kernels ----------------

__global__ void k_deg(const int* __restrict__ src, const int* __restrict__ dst,
                      int* __restrict__ deg, int* __restrict__ indeg){
  int e = blockIdx.x*blockDim.x + threadIdx.x;
  if(e < N_EDGES){
    atomicAdd(&deg[src[e]], 1);
    atomicAdd(&indeg[dst[e]], 1);
  }
}

__global__ void k_dis(const int* __restrict__ deg, float* __restrict__ dis){
  int i = blockIdx.x*blockDim.x + threadIdx.x;
  if(i < N_NODES){
    int d = deg[i];
    dis[i] = d > 0 ? rsqrtf((float)d) : 0.f;
  }
}

__global__ void k_edgew(const int* __restrict__ src, const int* __restrict__ dst,
                        const float* __restrict__ dis, float* __restrict__ w){
  int e = blockIdx.x*blockDim.x + threadIdx.x;
  if(e < N_EDGES){
    w[e] = -dis[src[e]] * dis[dst[e]];
  }
}

__global__ __launch_bounds__(1024) void k_scan(const int* __restrict__ cnt,
                                               int* __restrict__ offs,
                                               int* __restrict__ cursor){
  __shared__ int part[1024];
  const int n = N_NODES;
  const int CH = (n + 1023) / 1024;
  int tid = threadIdx.x;
  int base = tid * CH;
  int s = 0;
  for(int i = 0; i < CH; i++){
    int idx = base + i;
    if(idx < n) s += cnt[idx];
  }
  part[tid] = s;
  __syncthreads();
  for(int off = 1; off < 1024; off <<= 1){
    int v = (tid >= off) ? part[tid - off] : 0;
    __syncthreads();
    part[tid] += v;
    __syncthreads();
  }
  int run = (tid == 0) ? 0 : part[tid - 1];
  for(int i = 0; i < CH; i++){
    int idx = base + i;
    if(idx < n){
      offs[idx] = run;
      cursor[idx] = run;
      run += cnt[idx];
    }
  }
  if(tid == 1023) offs[n] = part[1023];
}

__global__ void k_scatter(const int* __restrict__ src, const int* __restrict__ dst,
                          const float* __restrict__ w, int* __restrict__ cursor,
                          int* __restrict__ csr_s, float* __restrict__ csr_w){
  int e = blockIdx.x*blockDim.x + threadIdx.x;
  if(e < N_EDGES){
    int d = dst[e];
    int p = atomicAdd(&cursor[d], 1);
    csr_s[p] = src[e];
    csr_w[p] = w[e];
  }
}

__global__ __launch_bounds__(128) void k_gbounds(const int* __restrict__ batch,
                                                 int* __restrict__ gstart,
                                                 int* __restrict__ gcnt){
  int g = threadIdx.x;
  if(g <= N_GRAPHS){
    int lo = 0, hi = N_NODES;
    while(lo < hi){
      int mid = (lo + hi) >> 1;
      if(batch[mid] < g) lo = mid + 1; else hi = mid;
    }
    gstart[g] = lo;
  }
  __syncthreads();
  if(g < N_GRAPHS) gcnt[g] = gstart[g + 1] - gstart[g];
}

// ---------------- propagation ----------------
// out[i,:] = alpha * sum_j w_j * bf16gather(Xb[src_j,:]) - (prev ? prev[i,:] : 0)
// Half-wave per node: 32 lanes x 16B (C=256) / 8B (C=128). 8 nodes per 256-thr block.

__device__ inline void fma8(float* a, uint4 v, float w){
  a[0] += w * bf2f(v.x & 0xffffu); a[1] += w * bf2f(v.x >> 16);
  a[2] += w * bf2f(v.y & 0xffffu); a[3] += w * bf2f(v.y >> 16);
  a[4] += w * bf2f(v.z & 0xffffu); a[5] += w * bf2f(v.z >> 16);
  a[6] += w * bf2f(v.w & 0xffffu); a[7] += w * bf2f(v.w >> 16);
}

__global__ __launch_bounds__(256) void k_prop256(float* __restrict__ out,
                                                 const __hip_bfloat16* __restrict__ Xb,
                                                 const float* __restrict__ prev,
                                                 const int* __restrict__ csr_s,
                                                 const float* __restrict__ csr_w,
                                                 const int* __restrict__ offs,
                                                 float alpha,
                                                 __hip_bfloat16* __restrict__ tx,
                                                 int tx_stride){
  int hl   = threadIdx.x & 31;
  int node = blockIdx.x * 8 + (threadIdx.x >> 5);
  int j0 = offs[node], j1 = offs[node + 1];
  float a[8] = {};
  const __hip_bfloat16* __restrict__ gbase = Xb + hl * 8;
  int j = j0;
  for(; j + 1 < j1; j += 2){
    int   s0 = csr_s[j],   s1 = csr_s[j + 1];
    float w0 = csr_w[j],   w1 = csr_w[j + 1];
    uint4 v0 = *(const uint4*)(gbase + (size_t)s0 * tx_stride);
    uint4 v1 = *(const uint4*)(gbase + (size_t)s1 * tx_stride);
    fma8(a, v0, w0);
    fma8(a, v1, w1);
  }
  if(j < j1){
    uint4 v0 = *(const uint4*)(gbase + (size_t)csr_s[j] * tx_stride);
    fma8(a, v0, csr_w[j]);
  }
  float r[8];
#pragma unroll
  for(int i = 0; i < 8; i++) r[i] = alpha * a[i];
  size_t off = (size_t)node * 256 + hl * 8;
  if(prev){
    float4 p0 = *(const float4*)(prev + off);
    float4 p1 = *(const float4*)(prev + off + 4);
    r[0] -= p0.x; r[1] -= p0.y; r[2] -= p0.z; r[3] -= p0.w;
    r[4] -= p1.x; r[5] -= p1.y; r[6] -= p1.z; r[7] -= p1.w;
  }
  *(float4*)(out + off)     = make_float4(r[0], r[1], r[2], r[3]);
  *(float4*)(out + off + 4) = make_float4(r[4], r[5], r[6], r[7]);
  uint4 ob;
  ob.x = (unsigned)f2bf_bits(r[0]) | ((unsigned)f2bf_bits(r[1]) << 16);
  ob.y = (unsigned)f2bf_bits(r[2]) | ((unsigned)f2bf_bits(r[3]) << 16);
  ob.z = (unsigned)f2bf_bits(r[4]) | ((unsigned)f2bf_bits(r[5]) << 16);
  ob.w = (unsigned)f2bf_bits(r[6]) | ((unsigned)f2bf_bits(r[7]) << 16);
  *(uint4*)(tx + (size_t)node * tx_stride + hl * 8) = ob;
}

__global__ __launch_bounds__(256) void k_prop128(float* __restrict__ out,
                                                 const __hip_bfloat16* __restrict__ Xb,
                                                 const float* __restrict__ prev,
                                                 const int* __restrict__ csr_s,
                                                 const float* __restrict__ csr_w,
                                                 const int* __restrict__ offs,
                                                 float alpha,
                                                 __hip_bfloat16* __restrict__ tx,
                                                 int tx_stride){
  int hl   = threadIdx.x & 31;
  int node = blockIdx.x * 8 + (threadIdx.x >> 5);
  int j0 = offs[node], j1 = offs[node + 1];
  float a0 = 0.f, a1 = 0.f, a2 = 0.f, a3 = 0.f;
  const __hip_bfloat16* __restrict__ gbase = Xb + hl * 4;
  int j = j0;
  for(; j + 1 < j1; j += 2){
    int   s0 = csr_s[j],   s1 = csr_s[j + 1];
    float w0 = csr_w[j],   w1 = csr_w[j + 1];
    uint2 v0 = *(const uint2*)(gbase + (size_t)s0 * tx_stride);
    uint2 v1 = *(const uint2*)(gbase + (size_t)s1 * tx_stride);
    a0 += w0 * bf2f(v0.x & 0xffffu); a1 += w0 * bf2f(v0.x >> 16);
    a2 += w0 * bf2f(v0.y & 0xffffu); a3 += w0 * bf2f(v0.y >> 16);
    a0 += w1 * bf2f(v1.x & 0xffffu); a1 += w1 * bf2f(v1.x >> 16);
    a2 += w1 * bf2f(v1.y & 0xffffu); a3 += w1 * bf2f(v1.y >> 16);
  }
  if(j < j1){
    float w0 = csr_w[j];
    uint2 v0 = *(const uint2*)(gbase + (size_t)csr_s[j] * tx_stride);
    a0 += w0 * bf2f(v0.x & 0xffffu); a1 += w0 * bf2f(v0.x >> 16);
    a2 += w0 * bf2f(v0.y & 0xffffu); a3 += w0 * bf2f(v0.y >> 16);
  }
  float r0 = alpha * a0, r1 = alpha * a1, r2 = alpha * a2, r3 = alpha * a3;
  size_t off = (size_t)node * 128 + hl * 4;
  if(prev){
    float4 pv = *(const float4*)(prev + off);
    r0 -= pv.x; r1 -= pv.y; r2 -= pv.z; r3 -= pv.w;
  }
  *(float4*)(out + off) = make_float4(r0, r1, r2, r3);
  uint2 ob;
  ob.x = (unsigned)f2bf_bits(r0) | ((unsigned)f2bf_bits(r1) << 16);
  ob.y = (unsigned)f2bf_bits(r2) | ((unsigned)f2bf_bits(r3) << 16);
  *(uint2*)(tx + (size_t)node * tx_stride + hl * 4) = ob;
}

// fp32 [rows][C] -> bf16 strided slot, vectorized
template<int C>
__global__ void k_f2bf(const float* __restrict__ X, __hip_bfloat16* __restrict__ tx,
                       int tx_stride){
  int idx = blockIdx.x * blockDim.x + threadIdx.x;
  const int GPR = C / 4;
  if(idx < N_NODES * GPR){
    int r = idx / GPR;
    int c = (idx - r * GPR) * 4;
    float4 v = *(const float4*)(X + (size_t)r * C + c);
    uint2 ob;
    ob.x = (unsigned)f2bf_bits(v.x) | ((unsigned)f2bf_bits(v.y) << 16);
    ob.y = (unsigned)f2bf_bits(v.z) | ((unsigned)f2bf_bits(v.w) << 16);
    *(uint2*)(tx + (size_t)r * tx_stride + c) = ob;
  }
}

// weight transpose + bf16: WT[o][kc] = W[kc][o], o in [0,256)
__global__ void k_wt(const float* __restrict__ W, __hip_bfloat16* __restrict__ WT, int Ktot){
  int idx = blockIdx.x * blockDim.x + threadIdx.x;
  if(idx < Ktot * 256){
    int o = idx / Ktot;
    int kc = idx - o * Ktot;
    WT[idx] = __float2bfloat16(W[(size_t)kc * 256 + o]);
  }
}

// ---------------- MFMA GEMM ----------------
// O[M][256] = relu( A[M][Ktot](bf16) @ BT[256][Ktot](bf16)^T + bias )
// grid(4 n-blocks fast, 157 m-blocks): 628 blocks; adjacent blocks share A rows.
// Block 64M x 64N, wave 32x32. XOR-swizzled LDS, stride 64.

__global__ __launch_bounds__(256) void k_gemm(const __hip_bfloat16* __restrict__ A,
                                              const __hip_bfloat16* __restrict__ BT,
                                              const float* __restrict__ bias,
                                              float* __restrict__ O,
                                              int M, int Ktot, int relu){
  __shared__ short As[64 * 64];
  __shared__ short Bs[64 * 64];
  int tid = threadIdx.x;
  int lane = tid & 63;
  int wave = tid >> 6;
  int col0 = blockIdx.x * 64;
  int row0 = blockIdx.y * 64;
  int l15 = lane & 15;
  int quad = lane >> 4;
  int wm = (wave & 1) * 32;
  int wn = (wave >> 1) * 32;

  f32x4 acc[2][2] = {};

  for(int k0 = 0; k0 < Ktot; k0 += 64){
#pragma unroll
    for(int i = 0; i < 2; i++){
      int e = tid + i * 256;
      int r = e >> 3, g = e & 7;
      uint4 v = make_uint4(0u, 0u, 0u, 0u);
      int gr = row0 + r;
      if(gr < M) v = *(const uint4*)(A + (size_t)gr * Ktot + k0 + g * 8);
      *(uint4*)(As + r * 64 + ((g ^ (r & 7)) * 8)) = v;
    }
#pragma unroll
    for(int i = 0; i < 2; i++){
      int e = tid + i * 256;
      int n = e >> 3, g = e & 7;
      uint4 v = *(const uint4*)(BT + (size_t)(col0 + n) * Ktot + k0 + g * 8);
      *(uint4*)(Bs + n * 64 + ((g ^ (n & 7)) * 8)) = v;
    }
    __syncthreads();
#pragma unroll
    for(int kk = 0; kk < 64; kk += 32){
      int g = (kk >> 3) + quad;
      short8 a[2], b[2];
#pragma unroll
      for(int mi = 0; mi < 2; mi++){
        int r = wm + mi * 16 + l15;
        a[mi] = *(const short8*)(As + r * 64 + ((g ^ (r & 7)) * 8));
      }
#pragma unroll
      for(int ni = 0; ni < 2; ni++){
        int n = wn + ni * 16 + l15;
        b[ni] = *(const short8*)(Bs + n * 64 + ((g ^ (n & 7)) * 8));
      }
#pragma unroll
      for(int mi = 0; mi < 2; mi++)
#pragma unroll
        for(int ni = 0; ni < 2; ni++)
          acc[mi][ni] = __builtin_amdgcn_mfma_f32_16x16x32_bf16(a[mi], b[ni], acc[mi][ni], 0, 0, 0);
    }
    __syncthreads();
  }

#pragma unroll
  for(int mi = 0; mi < 2; mi++){
#pragma unroll
    for(int ni = 0; ni < 2; ni++){
      int gcol = col0 + wn + ni * 16 + l15;
      float bv = bias[gcol];
#pragma unroll
      for(int r = 0; r < 4; r++){
        int grow = row0 + wm + mi * 16 + quad * 4 + r;
        if(grow < M){
          float v = acc[mi][ni][r] + bv;
          if(relu) v = fmaxf(v, 0.f);
          O[(size_t)grow * C_HID + gcol] = v;
        }
      }
    }
  }
}

// ---------------- pooling + head ----------------

__global__ __launch_bounds__(128) void k_pool(const float* __restrict__ h,
                                              const int* __restrict__ gstart,
                                              const int* __restrict__ gcnt,
                                              float* __restrict__ pooled){
  int g = blockIdx.x;
  int c = blockIdx.y * 128 + threadIdx.x;
  int s = gstart[g], cnt = gcnt[g];
  float acc = 0.f;
  for(int i = 0; i < cnt; i++) acc += h[(size_t)(s + i) * C_HID + c];
  pooled[g * C_HID + c] = acc / fmaxf((float)cnt, 1.f);
}

__global__ __launch_bounds__(128) void k_final(const float* __restrict__ pooled,
                                               const float* __restrict__ Wout,
                                               const float* __restrict__ bout,
                                               float* __restrict__ out){
  int g = blockIdx.x;
  int o = threadIdx.x;
  float acc = bout[o];
  for(int c = 0; c < C_HID; c++) acc += pooled[g * C_HID + c] * Wout[c * C_OUTC + o];
  out[g * C_OUTC + o] = acc;
}

// ---------------- host ----------------

extern "C" void kernel_launch(void* const* d_in, const int* in_sizes, int n_in,
                              void* d_out, int out_size, void* d_ws, size_t ws_size,
                              hipStream_t stream){
  const float* x    = (const float*)d_in[0];
  const float* W0   = (const float*)d_in[1];
  const float* b0   = (const float*)d_in[2];
  const float* W1   = (const float*)d_in[3];
  const float* b1   = (const float*)d_in[4];
  const float* W2   = (const float*)d_in[5];
  const float* b2   = (const float*)d_in[6];
  const float* Wout = (const float*)d_in[7];
  const float* bout = (const float*)d_in[8];
  const int*   ei   = (const int*)d_in[9];
  const int*   batch= (const int*)d_in[10];
  const int* src = ei;
  const int* dst = ei + N_EDGES;
  float* out = (float*)d_out;

  char* p = (char*)d_ws;
  auto alloc = [&](size_t bytes)->char*{ char* r = p; p += align_up(bytes, 256); return r; };

  int*   deg    = (int*)  alloc(N_NODES * 4);
  int*   indeg  = (int*)  alloc(N_NODES * 4);
  int*   offs   = (int*)  alloc((N_NODES + 1) * 4);
  int*   cursor = (int*)  alloc(N_NODES * 4);
  float* dis    = (float*)alloc(N_NODES * 4);
  float* w_e    = (float*)alloc(N_EDGES * 4);
  int*   csr_s  = (int*)  alloc(N_EDGES * 4);
  float* csr_w  = (float*)alloc(N_EDGES * 4);
  int*   gcnt   = (int*)  alloc(N_GRAPHS * 4);
  int*   gstart = (int*)  alloc((N_GRAPHS + 1) * 4);
  float* pooled = (float*)alloc(N_GRAPHS * C_HID * 4);

  __hip_bfloat16* txall = (__hip_bfloat16*)alloc((size_t)N_NODES * (KCHEB * C_HID) * 2);
  __hip_bfloat16* WT0   = (__hip_bfloat16*)alloc((size_t)KCHEB * C_IN  * C_HID * 2);
  __hip_bfloat16* WT1   = (__hip_bfloat16*)alloc((size_t)KCHEB * C_HID * C_HID * 2);
  __hip_bfloat16* WT2   = (__hip_bfloat16*)alloc((size_t)KCHEB * C_HID * C_HID * 2);
  float* s0 = (float*)alloc((size_t)N_NODES * C_HID * 4);
  float* s1 = (float*)alloc((size_t)N_NODES * C_HID * 4);
  float* s2 = (float*)alloc((size_t)N_NODES * C_HID * 4);
  float* Hb = (float*)alloc((size_t)N_NODES * C_HID * 4);

  hipMemsetAsync(deg,   0, N_NODES * 4, stream);
  hipMemsetAsync(indeg, 0, N_NODES * 4, stream);

  const int TB = 256;
  int egrid = (N_EDGES + TB - 1) / TB;
  int ngrid = (N_NODES + TB - 1) / TB;

  k_deg<<<egrid, TB, 0, stream>>>(src, dst, deg, indeg);
  k_dis<<<ngrid, TB, 0, stream>>>(deg, dis);
  k_edgew<<<egrid, TB, 0, stream>>>(src, dst, dis, w_e);
  k_scan<<<1, 1024, 0, stream>>>(indeg, offs, cursor);
  k_scatter<<<egrid, TB, 0, stream>>>(src, dst, w_e, cursor, csr_s, csr_w);
  k_gbounds<<<1, 128, 0, stream>>>(batch, gstart, gcnt);

  {
    int n0 = KCHEB * C_IN  * C_HID;
    int n1 = KCHEB * C_HID * C_HID;
    k_wt<<<(n0 + TB - 1) / TB, TB, 0, stream>>>(W0, WT0, KCHEB * C_IN);
    k_wt<<<(n1 + TB - 1) / TB, TB, 0, stream>>>(W1, WT1, KCHEB * C_HID);
    k_wt<<<(n1 + TB - 1) / TB, TB, 0, stream>>>(W2, WT2, KCHEB * C_HID);
  }

  auto run_layer = [&](const float* X, int Cin, const __hip_bfloat16* WT, const float* b,
                       float* O, int relu){
    const int Ktot = KCHEB * Cin;
    if(Cin == C_IN){
      int ng = N_NODES * (C_IN / 4);
      k_f2bf<C_IN><<<(ng + TB - 1) / TB, TB, 0, stream>>>(X, txall, Ktot);
    } else {
      int ng = N_NODES * (C_HID / 4);
      k_f2bf<C_HID><<<(ng + TB - 1) / TB, TB, 0, stream>>>(X, txall, Ktot);
    }
    if(Cin == C_IN)
      k_prop128<<<N_NODES / 8, 256, 0, stream>>>(s0, txall, nullptr, csr_s, csr_w, offs, 1.f,
                                                 txall + 1 * Cin, Ktot);
    else
      k_prop256<<<N_NODES / 8, 256, 0, stream>>>(s0, txall, nullptr, csr_s, csr_w, offs, 1.f,
                                                 txall + 1 * Cin, Ktot);
    const float* T0 = X;
    float* T1 = s0;
    float* rot[3] = {s0, s1, s2};
    for(int k = 2; k < KCHEB; k++){
      float* T2 = rot[(k - 1) % 3];
      const __hip_bfloat16* gsrc = txall + (size_t)(k - 1) * Cin;
      if(Cin == C_IN)
        k_prop128<<<N_NODES / 8, 256, 0, stream>>>(T2, gsrc, T0, csr_s, csr_w, offs, 2.f,
                                                   txall + (size_t)k * Cin, Ktot);
      else
        k_prop256<<<N_NODES / 8, 256, 0, stream>>>(T2, gsrc, T0, csr_s, csr_w, offs, 2.f,
                                                   txall + (size_t)k * Cin, Ktot);
      T0 = T1;
      T1 = T2;
    }
    dim3 ggrid(4, (N_NODES + 63) / 64);
    k_gemm<<<ggrid, 256, 0, stream>>>(txall, WT, b, O, N_NODES, Ktot, relu);
  };

  run_layer(x,  C_IN,  WT0, b0, Hb, 1);
  run_layer(Hb, C_HID, WT1, b1, Hb, 1);
  run_layer(Hb, C_HID, WT2, b2, Hb, 1);

  dim3 pgrid(N_GRAPHS, C_HID / 128);
  k_pool<<<pgrid, 128, 0, stream>>>(Hb, gstart, gcnt, pooled);
  k_final<<<N_GRAPHS, C_OUTC, 0, stream>>>(pooled, Wout, bout, out);
}

// Round 5
// 805.648 us; speedup vs baseline: 2.5825x; 1.1313x over previous
//
#include <hip/hip_runtime.h>
#include <hip/hip_bf16.h>
#include <cstdint>
#include <cstddef>

#define N_NODES 10000
#define N_EDGES 320000
#define N_GRAPHS 64
#define KCHEB 10
#define C_IN 128
#define C_HID 256
#define C_OUTC 128

static inline size_t align_up(size_t v, size_t a){ return (v + a - 1) / a * a; }

typedef __attribute__((ext_vector_type(8))) short short8;   // 8 bf16 = 4 VGPRs
typedef __attribute__((ext_vector_type(4))) float f32x4;

__device__ inline float bf2f(unsigned int bits16){
  union{ unsigned int i; float f; } v; v.i = bits16 << 16; return v.f;
}
__device__ inline unsigned short f2bf_bits(float f){
  __hip_bfloat16 h = __float2bfloat16(f);
  return *reinterpret_cast<unsigned short*>(&h);
}

// ---------------- graph setup kernels ----------------

__global__ void k_deg(const int* __restrict__ src, const int* __restrict__ dst,
                      int* __restrict__ deg, int* __restrict__ indeg){
  int e = blockIdx.x*blockDim.x + threadIdx.x;
  if(e < N_EDGES){
    atomicAdd(&deg[src[e]], 1);
    atomicAdd(&indeg[dst[e]], 1);
  }
}

__global__ void k_dis(const int* __restrict__ deg, float* __restrict__ dis){
  int i = blockIdx.x*blockDim.x + threadIdx.x;
  if(i < N_NODES){
    int d = deg[i];
    dis[i] = d > 0 ? rsqrtf((float)d) : 0.f;
  }
}

__global__ void k_edgew(const int* __restrict__ src, const int* __restrict__ dst,
                        const float* __restrict__ dis, float* __restrict__ w){
  int e = blockIdx.x*blockDim.x + threadIdx.x;
  if(e < N_EDGES){
    w[e] = -dis[src[e]] * dis[dst[e]];
  }
}

__global__ __launch_bounds__(1024) void k_scan(const int* __restrict__ cnt,
                                               int* __restrict__ offs,
                                               int* __restrict__ cursor){
  __shared__ int part[1024];
  const int n = N_NODES;
  const int CH = (n + 1023) / 1024;
  int tid = threadIdx.x;
  int base = tid * CH;
  int s = 0;
  for(int i = 0; i < CH; i++){
    int idx = base + i;
    if(idx < n) s += cnt[idx];
  }
  part[tid] = s;
  __syncthreads();
  for(int off = 1; off < 1024; off <<= 1){
    int v = (tid >= off) ? part[tid - off] : 0;
    __syncthreads();
    part[tid] += v;
    __syncthreads();
  }
  int run = (tid == 0) ? 0 : part[tid - 1];
  for(int i = 0; i < CH; i++){
    int idx = base + i;
    if(idx < n){
      offs[idx] = run;
      cursor[idx] = run;
      run += cnt[idx];
    }
  }
  if(tid == 1023) offs[n] = part[1023];
}

__global__ void k_scatter(const int* __restrict__ src, const int* __restrict__ dst,
                          const float* __restrict__ w, int* __restrict__ cursor,
                          int* __restrict__ csr_s, float* __restrict__ csr_w){
  int e = blockIdx.x*blockDim.x + threadIdx.x;
  if(e < N_EDGES){
    int d = dst[e];
    int p = atomicAdd(&cursor[d], 1);
    csr_s[p] = src[e];
    csr_w[p] = w[e];
  }
}

__global__ __launch_bounds__(128) void k_gbounds(const int* __restrict__ batch,
                                                 int* __restrict__ gstart,
                                                 int* __restrict__ gcnt){
  int g = threadIdx.x;
  if(g <= N_GRAPHS){
    int lo = 0, hi = N_NODES;
    while(lo < hi){
      int mid = (lo + hi) >> 1;
      if(batch[mid] < g) lo = mid + 1; else hi = mid;
    }
    gstart[g] = lo;
  }
  __syncthreads();
  if(g < N_GRAPHS) gcnt[g] = gstart[g + 1] - gstart[g];
}

// ---------------- propagation ----------------
// out[i,:] = alpha * sum_j w_j * bf16gather(Xb[src_j,:]) - (prev ? prev[i,:] : 0)
// Half-wave per node, edge loop unrolled x4 (4 gathers in flight).

__device__ inline void fma8(float* a, uint4 v, float w){
  a[0] += w * bf2f(v.x & 0xffffu); a[1] += w * bf2f(v.x >> 16);
  a[2] += w * bf2f(v.y & 0xffffu); a[3] += w * bf2f(v.y >> 16);
  a[4] += w * bf2f(v.z & 0xffffu); a[5] += w * bf2f(v.z >> 16);
  a[6] += w * bf2f(v.w & 0xffffu); a[7] += w * bf2f(v.w >> 16);
}

__global__ __launch_bounds__(256) void k_prop256(float* __restrict__ out,
                                                 const __hip_bfloat16* __restrict__ Xb,
                                                 const float* __restrict__ prev,
                                                 const int* __restrict__ csr_s,
                                                 const float* __restrict__ csr_w,
                                                 const int* __restrict__ offs,
                                                 float alpha,
                                                 __hip_bfloat16* __restrict__ tx,
                                                 int tx_stride){
  int hl   = threadIdx.x & 31;
  int node = blockIdx.x * 8 + (threadIdx.x >> 5);
  int j0 = offs[node], j1 = offs[node + 1];
  float a[8] = {};
  const __hip_bfloat16* __restrict__ gbase = Xb + hl * 8;
  int j = j0;
  for(; j + 3 < j1; j += 4){
    int   s0 = csr_s[j],   s1 = csr_s[j + 1], s2 = csr_s[j + 2], s3 = csr_s[j + 3];
    float w0 = csr_w[j],   w1 = csr_w[j + 1];
    float w2 = csr_w[j+2], w3 = csr_w[j + 3];
    uint4 v0 = *(const uint4*)(gbase + (size_t)s0 * tx_stride);
    uint4 v1 = *(const uint4*)(gbase + (size_t)s1 * tx_stride);
    uint4 v2 = *(const uint4*)(gbase + (size_t)s2 * tx_stride);
    uint4 v3 = *(const uint4*)(gbase + (size_t)s3 * tx_stride);
    fma8(a, v0, w0);
    fma8(a, v1, w1);
    fma8(a, v2, w2);
    fma8(a, v3, w3);
  }
  for(; j < j1; j++){
    uint4 v0 = *(const uint4*)(gbase + (size_t)csr_s[j] * tx_stride);
    fma8(a, v0, csr_w[j]);
  }
  float r[8];
#pragma unroll
  for(int i = 0; i < 8; i++) r[i] = alpha * a[i];
  size_t off = (size_t)node * 256 + hl * 8;
  if(prev){
    float4 p0 = *(const float4*)(prev + off);
    float4 p1 = *(const float4*)(prev + off + 4);
    r[0] -= p0.x; r[1] -= p0.y; r[2] -= p0.z; r[3] -= p0.w;
    r[4] -= p1.x; r[5] -= p1.y; r[6] -= p1.z; r[7] -= p1.w;
  }
  *(float4*)(out + off)     = make_float4(r[0], r[1], r[2], r[3]);
  *(float4*)(out + off + 4) = make_float4(r[4], r[5], r[6], r[7]);
  uint4 ob;
  ob.x = (unsigned)f2bf_bits(r[0]) | ((unsigned)f2bf_bits(r[1]) << 16);
  ob.y = (unsigned)f2bf_bits(r[2]) | ((unsigned)f2bf_bits(r[3]) << 16);
  ob.z = (unsigned)f2bf_bits(r[4]) | ((unsigned)f2bf_bits(r[5]) << 16);
  ob.w = (unsigned)f2bf_bits(r[6]) | ((unsigned)f2bf_bits(r[7]) << 16);
  *(uint4*)(tx + (size_t)node * tx_stride + hl * 8) = ob;
}

__global__ __launch_bounds__(256) void k_prop128(float* __restrict__ out,
                                                 const __hip_bfloat16* __restrict__ Xb,
                                                 const float* __restrict__ prev,
                                                 const int* __restrict__ csr_s,
                                                 const float* __restrict__ csr_w,
                                                 const int* __restrict__ offs,
                                                 float alpha,
                                                 __hip_bfloat16* __restrict__ tx,
                                                 int tx_stride){
  int hl   = threadIdx.x & 31;
  int node = blockIdx.x * 8 + (threadIdx.x >> 5);
  int j0 = offs[node], j1 = offs[node + 1];
  float a[4] = {};
  const __hip_bfloat16* __restrict__ gbase = Xb + hl * 4;
  int j = j0;
  for(; j + 3 < j1; j += 4){
    int   s0 = csr_s[j],   s1 = csr_s[j + 1], s2 = csr_s[j + 2], s3 = csr_s[j + 3];
    float w0 = csr_w[j],   w1 = csr_w[j + 1];
    float w2 = csr_w[j+2], w3 = csr_w[j + 3];
    uint2 v0 = *(const uint2*)(gbase + (size_t)s0 * tx_stride);
    uint2 v1 = *(const uint2*)(gbase + (size_t)s1 * tx_stride);
    uint2 v2 = *(const uint2*)(gbase + (size_t)s2 * tx_stride);
    uint2 v3 = *(const uint2*)(gbase + (size_t)s3 * tx_stride);
    a[0] += w0 * bf2f(v0.x & 0xffffu); a[1] += w0 * bf2f(v0.x >> 16);
    a[2] += w0 * bf2f(v0.y & 0xffffu); a[3] += w0 * bf2f(v0.y >> 16);
    a[0] += w1 * bf2f(v1.x & 0xffffu); a[1] += w1 * bf2f(v1.x >> 16);
    a[2] += w1 * bf2f(v1.y & 0xffffu); a[3] += w1 * bf2f(v1.y >> 16);
    a[0] += w2 * bf2f(v2.x & 0xffffu); a[1] += w2 * bf2f(v2.x >> 16);
    a[2] += w2 * bf2f(v2.y & 0xffffu); a[3] += w2 * bf2f(v2.y >> 16);
    a[0] += w3 * bf2f(v3.x & 0xffffu); a[1] += w3 * bf2f(v3.x >> 16);
    a[2] += w3 * bf2f(v3.y & 0xffffu); a[3] += w3 * bf2f(v3.y >> 16);
  }
  for(; j < j1; j++){
    float w0 = csr_w[j];
    uint2 v0 = *(const uint2*)(gbase + (size_t)csr_s[j] * tx_stride);
    a[0] += w0 * bf2f(v0.x & 0xffffu); a[1] += w0 * bf2f(v0.x >> 16);
    a[2] += w0 * bf2f(v0.y & 0xffffu); a[3] += w0 * bf2f(v0.y >> 16);
  }
  float r0 = alpha * a[0], r1 = alpha * a[1], r2 = alpha * a[2], r3 = alpha * a[3];
  size_t off = (size_t)node * 128 + hl * 4;
  if(prev){
    float4 pv = *(const float4*)(prev + off);
    r0 -= pv.x; r1 -= pv.y; r2 -= pv.z; r3 -= pv.w;
  }
  *(float4*)(out + off) = make_float4(r0, r1, r2, r3);
  uint2 ob;
  ob.x = (unsigned)f2bf_bits(r0) | ((unsigned)f2bf_bits(r1) << 16);
  ob.y = (unsigned)f2bf_bits(r2) | ((unsigned)f2bf_bits(r3) << 16);
  *(uint2*)(tx + (size_t)node * tx_stride + hl * 4) = ob;
}

// fp32 [rows][C] -> bf16 strided slot (layer-1 input only)
template<int C>
__global__ void k_f2bf(const float* __restrict__ X, __hip_bfloat16* __restrict__ tx,
                       int tx_stride){
  int idx = blockIdx.x * blockDim.x + threadIdx.x;
  const int GPR = C / 4;
  if(idx < N_NODES * GPR){
    int r = idx / GPR;
    int c = (idx - r * GPR) * 4;
    float4 v = *(const float4*)(X + (size_t)r * C + c);
    uint2 ob;
    ob.x = (unsigned)f2bf_bits(v.x) | ((unsigned)f2bf_bits(v.y) << 16);
    ob.y = (unsigned)f2bf_bits(v.z) | ((unsigned)f2bf_bits(v.w) << 16);
    *(uint2*)(tx + (size_t)r * tx_stride + c) = ob;
  }
}

// weight transpose + bf16: WT[o][kc] = W[kc][o], o in [0,256)
__global__ void k_wt(const float* __restrict__ W, __hip_bfloat16* __restrict__ WT, int Ktot){
  int idx = blockIdx.x * blockDim.x + threadIdx.x;
  if(idx < Ktot * 256){
    int o = idx / Ktot;
    int kc = idx - o * Ktot;
    WT[idx] = __float2bfloat16(W[(size_t)kc * 256 + o]);
  }
}

// ---------------- MFMA GEMM ----------------
// O[M][256] = relu( A[M][Ktot](bf16) @ BT[256][Ktot](bf16)^T + bias )
// Block tile 32M x 256N, grid 313: A fetched once from HBM; B hot in L2.
// Optional bf16 epilogue copy into tx2 (next layer's Tx0 slot).

__global__ __launch_bounds__(256) void k_gemm(const __hip_bfloat16* __restrict__ A,
                                              const __hip_bfloat16* __restrict__ BT,
                                              const float* __restrict__ bias,
                                              float* __restrict__ O,
                                              int M, int Ktot, int relu,
                                              __hip_bfloat16* __restrict__ tx2,
                                              int tx2_stride){
  __shared__ short As[32 * 64];
  __shared__ short Bs[256 * 64];
  int tid = threadIdx.x;
  int lane = tid & 63;
  int wave = tid >> 6;
  int row0 = blockIdx.x * 32;
  int l15 = lane & 15;
  int quad = lane >> 4;
  int wn = wave * 64;

  f32x4 acc[2][4] = {};

  for(int k0 = 0; k0 < Ktot; k0 += 64){
    {
      int r = tid >> 3, g = tid & 7;
      uint4 v = make_uint4(0u, 0u, 0u, 0u);
      int gr = row0 + r;
      if(gr < M) v = *(const uint4*)(A + (size_t)gr * Ktot + k0 + g * 8);
      *(uint4*)(As + r * 64 + ((g ^ (r & 7)) * 8)) = v;
    }
#pragma unroll
    for(int i = 0; i < 8; i++){
      int e = tid + i * 256;
      int n = e >> 3, g = e & 7;
      uint4 v = *(const uint4*)(BT + (size_t)n * Ktot + k0 + g * 8);
      *(uint4*)(Bs + n * 64 + ((g ^ (n & 7)) * 8)) = v;
    }
    __syncthreads();
#pragma unroll
    for(int kk = 0; kk < 64; kk += 32){
      int g = (kk >> 3) + quad;
      short8 a[2], b[4];
#pragma unroll
      for(int mi = 0; mi < 2; mi++){
        int r = mi * 16 + l15;
        a[mi] = *(const short8*)(As + r * 64 + ((g ^ (r & 7)) * 8));
      }
#pragma unroll
      for(int ni = 0; ni < 4; ni++){
        int n = wn + ni * 16 + l15;
        b[ni] = *(const short8*)(Bs + n * 64 + ((g ^ (n & 7)) * 8));
      }
#pragma unroll
      for(int mi = 0; mi < 2; mi++)
#pragma unroll
        for(int ni = 0; ni < 4; ni++)
          acc[mi][ni] = __builtin_amdgcn_mfma_f32_16x16x32_bf16(a[mi], b[ni], acc[mi][ni], 0, 0, 0);
    }
    __syncthreads();
  }

#pragma unroll
  for(int mi = 0; mi < 2; mi++){
#pragma unroll
    for(int ni = 0; ni < 4; ni++){
      int gcol = wn + ni * 16 + l15;
      float bv = bias[gcol];
#pragma unroll
      for(int r = 0; r < 4; r++){
        int grow = row0 + mi * 16 + quad * 4 + r;
        if(grow < M){
          float v = acc[mi][ni][r] + bv;
          if(relu) v = fmaxf(v, 0.f);
          O[(size_t)grow * C_HID + gcol] = v;
          if(tx2) tx2[(size_t)grow * tx2_stride + gcol] = __float2bfloat16(v);
        }
      }
    }
  }
}

// ---------------- pooling + head ----------------

__global__ __launch_bounds__(128) void k_pool(const float* __restrict__ h,
                                              const int* __restrict__ gstart,
                                              const int* __restrict__ gcnt,
                                              float* __restrict__ pooled){
  int g = blockIdx.x;
  int c = blockIdx.y * 128 + threadIdx.x;
  int s = gstart[g], cnt = gcnt[g];
  float acc = 0.f;
  for(int i = 0; i < cnt; i++) acc += h[(size_t)(s + i) * C_HID + c];
  pooled[g * C_HID + c] = acc / fmaxf((float)cnt, 1.f);
}

__global__ __launch_bounds__(128) void k_final(const float* __restrict__ pooled,
                                               const float* __restrict__ Wout,
                                               const float* __restrict__ bout,
                                               float* __restrict__ out){
  int g = blockIdx.x;
  int o = threadIdx.x;
  float acc = bout[o];
  for(int c = 0; c < C_HID; c++) acc += pooled[g * C_HID + c] * Wout[c * C_OUTC + o];
  out[g * C_OUTC + o] = acc;
}

// ---------------- host ----------------

extern "C" void kernel_launch(void* const* d_in, const int* in_sizes, int n_in,
                              void* d_out, int out_size, void* d_ws, size_t ws_size,
                              hipStream_t stream){
  const float* x    = (const float*)d_in[0];
  const float* W0   = (const float*)d_in[1];
  const float* b0   = (const float*)d_in[2];
  const float* W1   = (const float*)d_in[3];
  const float* b1   = (const float*)d_in[4];
  const float* W2   = (const float*)d_in[5];
  const float* b2   = (const float*)d_in[6];
  const float* Wout = (const float*)d_in[7];
  const float* bout = (const float*)d_in[8];
  const int*   ei   = (const int*)d_in[9];
  const int*   batch= (const int*)d_in[10];
  const int* src = ei;
  const int* dst = ei + N_EDGES;
  float* out = (float*)d_out;

  char* p = (char*)d_ws;
  auto alloc = [&](size_t bytes)->char*{ char* r = p; p += align_up(bytes, 256); return r; };

  int*   deg    = (int*)  alloc(N_NODES * 4);
  int*   indeg  = (int*)  alloc(N_NODES * 4);
  int*   offs   = (int*)  alloc((N_NODES + 1) * 4);
  int*   cursor = (int*)  alloc(N_NODES * 4);
  float* dis    = (float*)alloc(N_NODES * 4);
  float* w_e    = (float*)alloc(N_EDGES * 4);
  int*   csr_s  = (int*)  alloc(N_EDGES * 4);
  float* csr_w  = (float*)alloc(N_EDGES * 4);
  int*   gcnt   = (int*)  alloc(N_GRAPHS * 4);
  int*   gstart = (int*)  alloc((N_GRAPHS + 1) * 4);
  float* pooled = (float*)alloc(N_GRAPHS * C_HID * 4);

  __hip_bfloat16* txall = (__hip_bfloat16*)alloc((size_t)N_NODES * (KCHEB * C_HID) * 2);
  __hip_bfloat16* WT0   = (__hip_bfloat16*)alloc((size_t)KCHEB * C_IN  * C_HID * 2);
  __hip_bfloat16* WT1   = (__hip_bfloat16*)alloc((size_t)KCHEB * C_HID * C_HID * 2);
  __hip_bfloat16* WT2   = (__hip_bfloat16*)alloc((size_t)KCHEB * C_HID * C_HID * 2);
  float* s0 = (float*)alloc((size_t)N_NODES * C_HID * 4);
  float* s1 = (float*)alloc((size_t)N_NODES * C_HID * 4);
  float* s2 = (float*)alloc((size_t)N_NODES * C_HID * 4);
  float* Hb = (float*)alloc((size_t)N_NODES * C_HID * 4);

  hipMemsetAsync(deg,   0, N_NODES * 4, stream);
  hipMemsetAsync(indeg, 0, N_NODES * 4, stream);

  const int TB = 256;
  int egrid = (N_EDGES + TB - 1) / TB;
  int ngrid = (N_NODES + TB - 1) / TB;

  k_deg<<<egrid, TB, 0, stream>>>(src, dst, deg, indeg);
  k_dis<<<ngrid, TB, 0, stream>>>(deg, dis);
  k_edgew<<<egrid, TB, 0, stream>>>(src, dst, dis, w_e);
  k_scan<<<1, 1024, 0, stream>>>(indeg, offs, cursor);
  k_scatter<<<egrid, TB, 0, stream>>>(src, dst, w_e, cursor, csr_s, csr_w);
  k_gbounds<<<1, 128, 0, stream>>>(batch, gstart, gcnt);

  {
    int n0 = KCHEB * C_IN  * C_HID;
    int n1 = KCHEB * C_HID * C_HID;
    k_wt<<<(n0 + TB - 1) / TB, TB, 0, stream>>>(W0, WT0, KCHEB * C_IN);
    k_wt<<<(n1 + TB - 1) / TB, TB, 0, stream>>>(W1, WT1, KCHEB * C_HID);
    k_wt<<<(n1 + TB - 1) / TB, TB, 0, stream>>>(W2, WT2, KCHEB * C_HID);
  }

  const int K128 = KCHEB * C_IN;   // 1280
  const int K256 = KCHEB * C_HID;  // 2560

  // ---- layer 1 (Cin=128) ----
  {
    int ng = N_NODES * (C_IN / 4);
    k_f2bf<C_IN><<<(ng + TB - 1) / TB, TB, 0, stream>>>(x, txall, K128);
    k_prop128<<<N_NODES / 8, 256, 0, stream>>>(s0, txall, nullptr, csr_s, csr_w, offs, 1.f,
                                               txall + C_IN, K128);
    const float* T0 = x;
    float* T1 = s0;
    float* rot[3] = {s0, s1, s2};
    for(int k = 2; k < KCHEB; k++){
      float* T2 = rot[(k - 1) % 3];
      k_prop128<<<N_NODES / 8, 256, 0, stream>>>(T2, txall + (size_t)(k - 1) * C_IN, T0,
                                                 csr_s, csr_w, offs, 2.f,
                                                 txall + (size_t)k * C_IN, K128);
      T0 = T1; T1 = T2;
    }
    // GEMM -> Hb (fp32) + txall slot0 for layer 2 (stride K256)
    k_gemm<<<(N_NODES + 31) / 32, 256, 0, stream>>>(txall, WT0, b0, Hb, N_NODES, K128, 1,
                                                    txall, K256);
  }

  // ---- layers 2,3 (Cin=256) ----
  for(int layer = 1; layer < 3; layer++){
    const __hip_bfloat16* WT = (layer == 1) ? WT1 : WT2;
    const float* b = (layer == 1) ? b1 : b2;
    k_prop256<<<N_NODES / 8, 256, 0, stream>>>(s0, txall, nullptr, csr_s, csr_w, offs, 1.f,
                                               txall + C_HID, K256);
    const float* T0 = Hb;
    float* T1 = s0;
    float* rot[3] = {s0, s1, s2};
    for(int k = 2; k < KCHEB; k++){
      float* T2 = rot[(k - 1) % 3];
      k_prop256<<<N_NODES / 8, 256, 0, stream>>>(T2, txall + (size_t)(k - 1) * C_HID, T0,
                                                 csr_s, csr_w, offs, 2.f,
                                                 txall + (size_t)k * C_HID, K256);
      T0 = T1; T1 = T2;
    }
    // last layer doesn't need a bf16 copy of its output
    __hip_bfloat16* tx2 = (layer == 1) ? txall : nullptr;
    k_gemm<<<(N_NODES + 31) / 32, 256, 0, stream>>>(txall, WT, b, Hb, N_NODES, K256, 1,
                                                    tx2, K256);
  }

  dim3 pgrid(N_GRAPHS, C_HID / 128);
  k_pool<<<pgrid, 128, 0, stream>>>(Hb, gstart, gcnt, pooled);
  k_final<<<N_GRAPHS, C_OUTC, 0, stream>>>(pooled, Wout, bout, out);
}